// Round 14
// baseline (136.542 us; speedup 1.0000x reference)
//
#include <hip/hip_runtime.h>
#include <hip/hip_fp16.h>

#define NFEAT 128
#define NOUT  64
#define PCAP  128      // padded slots per node; mean in-deg 64, P(Poisson(64)>128)~5e-13 (guarded)
#define HB    256      // edge-chunk blocks for hist/scatter, 2500 edges each
#define NPB   8        // nodes per fused gather+MLP block (8 waves x 1 node, TPB=512)

// ---- pass A: ONE edge pass; packed 16/16 LDS counters (dst=low, src=high);
//      TPB=1024 (R10-proven).
__global__ void hist_kernel(const int* __restrict__ src, const int* __restrict__ dst,
                            unsigned char* __restrict__ hist_src,
                            unsigned char* __restrict__ hist_dst,
                            int nN, int nE) {
    extern __shared__ int bins[];  // nN ints = 40 KB; low16=dst count, high16=src count
    int b = blockIdx.x;
    int per = (nE + HB - 1) / HB;
    int lo = b * per, hi = min(lo + per, nE);
    for (int i = threadIdx.x; i < nN; i += blockDim.x) bins[i] = 0;
    __syncthreads();
    for (int e = lo + threadIdx.x; e < hi; e += blockDim.x) {
        int s = src[e], d = dst[e];
        atomicAdd(&bins[d], 1);        // chunk <= 2500, low field never carries
        atomicAdd(&bins[s], 0x10000);
    }
    __syncthreads();
    for (int i = threadIdx.x; i < nN; i += blockDim.x) {
        int v = bins[i];
        hist_dst[(size_t)b * nN + i] = (unsigned char)min(v & 0xFFFF, 255);
        hist_src[(size_t)b * nN + i] = (unsigned char)min(v >> 16, 255);
    }
}

// ---- pass B: wave-per-4-nodes, SIMD-in-register packed-byte scan (R10-proven).
__global__ void offsets_kernel(const unsigned char* __restrict__ hist_src,
                               const unsigned char* __restrict__ hist_dst,
                               unsigned char* __restrict__ base_rel,
                               unsigned short* __restrict__ deg_in,
                               float* __restrict__ rs_in, float* __restrict__ rs_out, int nN) {
    int tid = blockIdx.x * blockDim.x + threadIdx.x;
    int wid = tid >> 6;            // one wave per 4-node group
    int lane = tid & 63;
    int i0 = wid * 4;
    if (i0 >= nN) return;
    int c0 = lane * 4;             // this lane's 4 chunks (64 lanes x 4 = 256 = HB)
    unsigned int d[4], s4[4];
#pragma unroll
    for (int u = 0; u < 4; u++) {
        d[u]  = *(const unsigned int*)&hist_dst[(size_t)(c0 + u) * nN + i0];
        s4[u] = *(const unsigned int*)&hist_src[(size_t)(c0 + u) * nN + i0];
    }
    unsigned int run = 0, pre[4];
#pragma unroll
    for (int u = 0; u < 4; u++) { pre[u] = run; run += d[u]; }   // packed byte adds
    unsigned int ssum = s4[0] + s4[1] + s4[2] + s4[3];
    unsigned int inc = run;
#pragma unroll
    for (int off = 1; off < 64; off <<= 1) {
        unsigned int t = (unsigned int)__shfl_up((int)inc, off);
        if (lane >= off) inc += t;
    }
    unsigned int excl = inc - run;
#pragma unroll
    for (int u = 0; u < 4; u++)
        *(unsigned int*)&base_rel[(size_t)(c0 + u) * nN + i0] = excl + pre[u];
    unsigned int dtot = (unsigned int)__shfl((int)inc, 63);  // packed dst totals
#pragma unroll
    for (int off = 1; off < 64; off <<= 1)
        ssum += (unsigned int)__shfl_xor((int)ssum, off);    // packed src totals
    if (lane < 4) {                // lane u finalizes node i0+u
        int i = i0 + lane;
        int dg = (dtot >> (8 * lane)) & 0xFF;
        int sg = (ssum >> (8 * lane)) & 0xFF;
        deg_in[i] = (unsigned short)min(dg, PCAP);
        rs_in[i]  = rsqrtf(fmaxf((float)dg, 1.0f));
        rs_out[i] = rsqrtf(fmaxf((float)sg, 1.0f));
    }
}

// ---- pass C: scatter edges into dense padded CSR via LDS cursors (TPB=1024, R10-proven).
//      Tail: fused x -> fp16 PRE-SCALED by rs_out.
__global__ void scatter_kernel(const int* __restrict__ src, const int* __restrict__ dst,
                               const unsigned char* __restrict__ base_rel,
                               const float* __restrict__ x, const float* __restrict__ rs_out,
                               unsigned short* __restrict__ csr, uint4* __restrict__ xh,
                               int nN, int nE) {
    extern __shared__ int cur[];  // nN ints = 40 KB
    int b = blockIdx.x;
    int per = (nE + HB - 1) / HB;
    int lo = b * per, hi = min(lo + per, nE);
    for (int i = threadIdx.x; i < nN; i += blockDim.x)
        cur[i] = base_rel[(size_t)b * nN + i];
    __syncthreads();
    for (int e = lo + threadIdx.x; e < hi; e += blockDim.x) {
        int s = src[e], d = dst[e];
        int pos = atomicAdd(&cur[d], 1);  // LDS atomic; chunk's slot range globally disjoint
        if (pos < PCAP)
            csr[(size_t)d * PCAP + pos] = (unsigned short)s;
    }
    // fused x -> fp16 * rs_out[row] (8 floats -> 8 halves per chunk), grid-stride
    const float4* xf = (const float4*)x;
    int nchunk = nN * NFEAT / 8;
    for (int c = blockIdx.x * blockDim.x + threadIdx.x; c < nchunk; c += gridDim.x * blockDim.x) {
        int row = c >> 4;              // 16 8-float chunks per 128-feat row
        float rs = rs_out[row];
        float4 a = xf[2 * c], bb = xf[2 * c + 1];
        __half2 h[4] = {__floats2half2_rn(a.x * rs, a.y * rs),
                        __floats2half2_rn(a.z * rs, a.w * rs),
                        __floats2half2_rn(bb.x * rs, bb.y * rs),
                        __floats2half2_rn(bb.z * rs, bb.w * rs)};
        xh[c] = *(uint4*)h;
    }
}

__device__ __forceinline__ void add8(float* acc, uint4 v) {
    const __half2* h = (const __half2*)&v;
    float2 p0 = __half22float2(h[0]), p1 = __half22float2(h[1]);
    float2 p2 = __half22float2(h[2]), p3 = __half22float2(h[3]);
    acc[0] += p0.x; acc[1] += p0.y; acc[2] += p1.x; acc[3] += p1.y;
    acc[4] += p2.x; acc[5] += p2.y; acc[6] += p3.x; acc[7] += p3.y;
}

// ---- FUSED layer-1 gather SpMM + dense MLP. R14: TPB=512, 8 waves x ONE node.
//      Concurrency ladder (2500 w @133.9 -> 5000 w @130.2) continued to 10000 waves
//      WITHOUT doubling W1/W2 re-reads (grid stays 1250) and WITHOUT R11's convoy
//      (8 single-node waves, fine 512-thr granularity). No r-loop -> eids is pure
//      write-once/read-many; sched_barrier(0) retained vs R6-class compiler hoist.
__global__ void gather_mlp_kernel(const unsigned short* __restrict__ deg_in,
                                  const unsigned short* __restrict__ csr,
                                  const uint4* __restrict__ xh,
                                  const float* __restrict__ rs_out,
                                  const float* __restrict__ rs_in,
                                  const float* __restrict__ W1, const float* __restrict__ b1,
                                  const float* __restrict__ W2, __half* __restrict__ zh,
                                  int nN) {
    __shared__ float ts[NPB][NFEAT];            // 4 KB gather outputs
    __shared__ float h1[NPB][NFEAT];            // 4 KB hidden layer
    __shared__ unsigned short eids[NPB][PCAP];  // 2 KB (one row per wave)
    int tid = threadIdx.x;
    int w = tid >> 6, lane = tid & 63;          // 8 waves
    int i0 = blockIdx.x * NPB;                  // grid exact: nN/8
    int i = i0 + w;                             // this wave's node
    int quad = lane >> 4;   // edge residue class
    int g = lane & 15;      // 16B chunk within 256B fp16 row

    {
        int n = deg_in[i];
        ((unsigned int*)eids[w])[lane] =
            ((const unsigned int*)(csr + (size_t)i * PCAP))[lane];
        __builtin_amdgcn_sched_barrier(0);  // compiler fence (R12-proven)
        float s_in = rs_in[i];
        float acc[8] = {0.f, 0.f, 0.f, 0.f, 0.f, 0.f, 0.f, 0.f};
        int e = quad;
        for (; e + 28 < n; e += 32) {          // 8 edges of this quad in flight
            uint4 vv[8];
#pragma unroll
            for (int u = 0; u < 8; u++) {
                int s = eids[w][e + 4 * u];
                vv[u] = xh[(size_t)s * 16 + g];
            }
#pragma unroll
            for (int u = 0; u < 8; u++) add8(acc, vv[u]);
        }
        for (; e + 12 < n; e += 16) {
            uint4 vv[4];
#pragma unroll
            for (int u = 0; u < 4; u++) {
                int s = eids[w][e + 4 * u];
                vv[u] = xh[(size_t)s * 16 + g];
            }
#pragma unroll
            for (int u = 0; u < 4; u++) add8(acc, vv[u]);
        }
        for (; e < n; e += 4)
            add8(acc, xh[(size_t)eids[w][e] * 16 + g]);
#pragma unroll
        for (int d = 16; d <= 32; d <<= 1)
#pragma unroll
            for (int k = 0; k < 8; k++) acc[k] += __shfl_xor(acc[k], d);
        if (lane < 16) {
            float4 o0 = {acc[0] * s_in, acc[1] * s_in, acc[2] * s_in, acc[3] * s_in};
            float4 o1 = {acc[4] * s_in, acc[5] * s_in, acc[6] * s_in, acc[7] * s_in};
            float4* tp = (float4*)(&ts[w][g * 8]);
            tp[0] = o0; tp[1] = o1;
        }
    }
    __syncthreads();   // cross-wave: all 8 ts rows visible before MLP
    // ---- MLP tile, 512 threads, 8 nodes. Layer 1: 2 outputs/thread.
    {
        int j = tid & 127;
        int gq = (tid >> 7) * 2;               // nodes gq, gq+1 (0,2,4,6)
        float a0 = b1[j], a1 = a0;
#pragma unroll 8
        for (int k = 0; k < NFEAT; k++) {
            float wv = W1[k * NFEAT + j];
            a0 += ts[gq][k] * wv;
            a1 += ts[gq + 1][k] * wv;
        }
        h1[gq][j] = fmaxf(a0, 0.0f);
        h1[gq + 1][j] = fmaxf(a1, 0.0f);
    }
    __syncthreads();
    // ---- Layer 2: 1 output/thread (8 nodes x 64 outs), write fp16 z
    {
        int j2 = tid & 63;
        int n2 = tid >> 6;                     // node index 0..7
        float c = 0.f;
#pragma unroll 8
        for (int k = 0; k < NFEAT; k++)
            c += h1[n2][k] * W2[k * NOUT + j2];
        zh[(size_t)(i0 + n2) * NOUT + j2] = __float2half_rn(c * rs_out[i0 + n2]);
    }
}

// ---- layer-2 gather SpMM: wave/node, 8 lanes/edge x 16B (R10-verbatim)
__global__ void gather2_kernel(const unsigned short* __restrict__ deg_in,
                               const unsigned short* __restrict__ csr,
                               const uint4* __restrict__ zh, const float* __restrict__ rs_in,
                               const float* __restrict__ b2, float* __restrict__ out, int nN) {
    __shared__ unsigned short eids[4][PCAP];
    int tid = threadIdx.x;
    int w = tid >> 6, lane = tid & 63;
    int i = blockIdx.x * 4 + w;
    int n = deg_in[i];
    ((unsigned int*)eids[w])[lane] = ((const unsigned int*)(csr + (size_t)i * PCAP))[lane];
    // no barrier: wave-private LDS, write-once/read-many (proven)

    int oct = lane >> 3;   // edge residue class (0..7)
    int g = lane & 7;      // 16B chunk within 128B fp16 row
    float acc[8] = {0.f, 0.f, 0.f, 0.f, 0.f, 0.f, 0.f, 0.f};
    int e = oct;
    for (; e + 56 < n; e += 64) {
        uint4 vv[8];
#pragma unroll
        for (int u = 0; u < 8; u++) vv[u] = zh[(size_t)eids[w][e + 8 * u] * 8 + g];
#pragma unroll
        for (int u = 0; u < 8; u++) add8(acc, vv[u]);
    }
    for (; e + 24 < n; e += 32) {
        uint4 vv[4];
#pragma unroll
        for (int u = 0; u < 4; u++) vv[u] = zh[(size_t)eids[w][e + 8 * u] * 8 + g];
#pragma unroll
        for (int u = 0; u < 4; u++) add8(acc, vv[u]);
    }
    for (; e < n; e += 8)
        add8(acc, zh[(size_t)eids[w][e] * 8 + g]);
#pragma unroll
    for (int d = 8; d <= 32; d <<= 1)
#pragma unroll
        for (int k = 0; k < 8; k++) acc[k] += __shfl_xor(acc[k], d);
    if (lane < 8) {
        float s = rs_in[i];
        float4 bb0 = ((const float4*)b2)[2 * g], bb1 = ((const float4*)b2)[2 * g + 1];
        float4 o0 = {acc[0] * s + bb0.x, acc[1] * s + bb0.y, acc[2] * s + bb0.z, acc[3] * s + bb0.w};
        float4 o1 = {acc[4] * s + bb1.x, acc[5] * s + bb1.y, acc[6] * s + bb1.z, acc[7] * s + bb1.w};
        float4* op = (float4*)(out + (size_t)i * NOUT + g * 8);
        op[0] = o0; op[1] = o1;
    }
}

extern "C" void kernel_launch(void* const* d_in, const int* in_sizes, int n_in,
                              void* d_out, int out_size, void* d_ws, size_t ws_size,
                              hipStream_t stream) {
    const float* x  = (const float*)d_in[0];
    const int* src  = (const int*)d_in[1];
    const int* dst  = (const int*)d_in[2];
    const float* W1 = (const float*)d_in[3];
    const float* b1 = (const float*)d_in[4];
    const float* W2 = (const float*)d_in[5];
    const float* b2 = (const float*)d_in[6];
    float* out = (float*)d_out;

    const int nN = in_sizes[0] / NFEAT;  // 10000
    const int nE = in_sizes[1];          // 640000

    // ---- workspace (~14.7 MB), byte-identical layout to R10/R12/R13
    char* p = (char*)d_ws;
    uint4* xh = (uint4*)p;                        p += (size_t)nN * NFEAT * 2;  // 2.56 MB fp16 (pre-scaled)
    unsigned char* hist_src = (unsigned char*)p;  p += (size_t)HB * nN;         // 2.56 MB
    unsigned char* hist_dst = (unsigned char*)p;  p += (size_t)HB * nN;         // 2.56 MB
    unsigned char* base_rel = (unsigned char*)p;  p += (size_t)HB * nN;         // 2.56 MB
    unsigned short* csr     = (unsigned short*)p; p += (size_t)nN * PCAP * 2;   // 2.56 MB
    unsigned short* deg_in  = (unsigned short*)p; p += (size_t)nN * 2;          // 20 KB
    float* rs_in  = (float*)p; p += (size_t)nN * sizeof(float);
    float* rs_out = (float*)p; p += (size_t)nN * sizeof(float);
    __half* zh = (__half*)p;   p += (size_t)nN * NOUT * 2;                      // 1.28 MB fp16

    // 1. histograms (TPB=1024)
    hist_kernel<<<HB, 1024, (size_t)nN * sizeof(int), stream>>>(
        src, dst, hist_src, hist_dst, nN, nE);
    // 2. bases + degrees + rsqrt (wave-per-4-nodes packed scan)
    {
        int waves = nN / 4;                       // 2500
        int blocks = (waves * 64 + 255) / 256;    // 625
        offsets_kernel<<<blocks, 256, 0, stream>>>(
            hist_src, hist_dst, base_rel, deg_in, rs_in, rs_out, nN);
    }
    // 3. scatter into CSR + fused x->fp16 pre-scaled (TPB=1024)
    scatter_kernel<<<HB, 1024, (size_t)nN * sizeof(int), stream>>>(
        src, dst, base_rel, x, rs_out, csr, xh, nN, nE);
    // 4. FUSED layer-1 gather SpMM + MLP (TPB=512, 8 waves x 1 node: 10000 waves,
    //    grid 1250 — same weight traffic as R13, 2x wave residency)
    gather_mlp_kernel<<<nN / NPB, 512, 0, stream>>>(
        deg_in, csr, xh, rs_out, rs_in, W1, b1, W2, zh, nN);
    // 5. layer-2 gather SpMM (R10-verbatim)
    gather2_kernel<<<nN / 4, 256, 0, stream>>>(
        deg_in, csr, (const uint4*)zh, rs_in, b2, out, nN);
}

// Round 15
// 129.956 us; speedup vs baseline: 1.0507x; 1.0507x over previous
//
#include <hip/hip_runtime.h>
#include <hip/hip_fp16.h>

#define NFEAT 128
#define NOUT  64
#define PCAP  128      // padded slots per node; mean in-deg 64, P(Poisson(64)>128)~5e-13 (guarded)
#define HB    256      // edge-chunk blocks for hist/scatter, 2500 edges each
#define NPB   8        // nodes per fused gather+MLP block (4 waves x 2 nodes)

// ---- pass A: ONE edge pass; packed 16/16 LDS counters (dst=low, src=high);
//      TPB=1024 (R10-proven: serial LDS phases at 4 waves were latency-bound).
__global__ void hist_kernel(const int* __restrict__ src, const int* __restrict__ dst,
                            unsigned char* __restrict__ hist_src,
                            unsigned char* __restrict__ hist_dst,
                            int nN, int nE) {
    extern __shared__ int bins[];  // nN ints = 40 KB; low16=dst count, high16=src count
    int b = blockIdx.x;
    int per = (nE + HB - 1) / HB;
    int lo = b * per, hi = min(lo + per, nE);
    for (int i = threadIdx.x; i < nN; i += blockDim.x) bins[i] = 0;
    __syncthreads();
    for (int e = lo + threadIdx.x; e < hi; e += blockDim.x) {
        int s = src[e], d = dst[e];
        atomicAdd(&bins[d], 1);        // chunk <= 2500, low field never carries
        atomicAdd(&bins[s], 0x10000);
    }
    __syncthreads();
    for (int i = threadIdx.x; i < nN; i += blockDim.x) {
        int v = bins[i];
        hist_dst[(size_t)b * nN + i] = (unsigned char)min(v & 0xFFFF, 255);
        hist_src[(size_t)b * nN + i] = (unsigned char)min(v >> 16, 255);
    }
}

// ---- pass B: wave-per-4-nodes, SIMD-in-register packed-byte scan (R10-proven).
__global__ void offsets_kernel(const unsigned char* __restrict__ hist_src,
                               const unsigned char* __restrict__ hist_dst,
                               unsigned char* __restrict__ base_rel,
                               unsigned short* __restrict__ deg_in,
                               float* __restrict__ rs_in, float* __restrict__ rs_out, int nN) {
    int tid = blockIdx.x * blockDim.x + threadIdx.x;
    int wid = tid >> 6;            // one wave per 4-node group
    int lane = tid & 63;
    int i0 = wid * 4;
    if (i0 >= nN) return;
    int c0 = lane * 4;             // this lane's 4 chunks (64 lanes x 4 = 256 = HB)
    unsigned int d[4], s4[4];
#pragma unroll
    for (int u = 0; u < 4; u++) {
        d[u]  = *(const unsigned int*)&hist_dst[(size_t)(c0 + u) * nN + i0];
        s4[u] = *(const unsigned int*)&hist_src[(size_t)(c0 + u) * nN + i0];
    }
    unsigned int run = 0, pre[4];
#pragma unroll
    for (int u = 0; u < 4; u++) { pre[u] = run; run += d[u]; }   // packed byte adds
    unsigned int ssum = s4[0] + s4[1] + s4[2] + s4[3];
    unsigned int inc = run;
#pragma unroll
    for (int off = 1; off < 64; off <<= 1) {
        unsigned int t = (unsigned int)__shfl_up((int)inc, off);
        if (lane >= off) inc += t;
    }
    unsigned int excl = inc - run;
#pragma unroll
    for (int u = 0; u < 4; u++)
        *(unsigned int*)&base_rel[(size_t)(c0 + u) * nN + i0] = excl + pre[u];
    unsigned int dtot = (unsigned int)__shfl((int)inc, 63);  // packed dst totals
#pragma unroll
    for (int off = 1; off < 64; off <<= 1)
        ssum += (unsigned int)__shfl_xor((int)ssum, off);    // packed src totals
    if (lane < 4) {                // lane u finalizes node i0+u
        int i = i0 + lane;
        int dg = (dtot >> (8 * lane)) & 0xFF;
        int sg = (ssum >> (8 * lane)) & 0xFF;
        deg_in[i] = (unsigned short)min(dg, PCAP);
        rs_in[i]  = rsqrtf(fmaxf((float)dg, 1.0f));
        rs_out[i] = rsqrtf(fmaxf((float)sg, 1.0f));
    }
}

// ---- pass C: scatter edges into dense padded CSR via LDS cursors (TPB=1024, R10-proven).
//      Tail: fused x -> fp16 PRE-SCALED by rs_out.
__global__ void scatter_kernel(const int* __restrict__ src, const int* __restrict__ dst,
                               const unsigned char* __restrict__ base_rel,
                               const float* __restrict__ x, const float* __restrict__ rs_out,
                               unsigned short* __restrict__ csr, uint4* __restrict__ xh,
                               int nN, int nE) {
    extern __shared__ int cur[];  // nN ints = 40 KB
    int b = blockIdx.x;
    int per = (nE + HB - 1) / HB;
    int lo = b * per, hi = min(lo + per, nE);
    for (int i = threadIdx.x; i < nN; i += blockDim.x)
        cur[i] = base_rel[(size_t)b * nN + i];
    __syncthreads();
    for (int e = lo + threadIdx.x; e < hi; e += blockDim.x) {
        int s = src[e], d = dst[e];
        int pos = atomicAdd(&cur[d], 1);  // LDS atomic; chunk's slot range globally disjoint
        if (pos < PCAP)
            csr[(size_t)d * PCAP + pos] = (unsigned short)s;
    }
    // fused x -> fp16 * rs_out[row] (8 floats -> 8 halves per chunk), grid-stride
    const float4* xf = (const float4*)x;
    int nchunk = nN * NFEAT / 8;
    for (int c = blockIdx.x * blockDim.x + threadIdx.x; c < nchunk; c += gridDim.x * blockDim.x) {
        int row = c >> 4;              // 16 8-float chunks per 128-feat row
        float rs = rs_out[row];
        float4 a = xf[2 * c], bb = xf[2 * c + 1];
        __half2 h[4] = {__floats2half2_rn(a.x * rs, a.y * rs),
                        __floats2half2_rn(a.z * rs, a.w * rs),
                        __floats2half2_rn(bb.x * rs, bb.y * rs),
                        __floats2half2_rn(bb.z * rs, bb.w * rs)};
        xh[c] = *(uint4*)h;
    }
}

__device__ __forceinline__ void add8(float* acc, uint4 v) {
    const __half2* h = (const __half2*)&v;
    float2 p0 = __half22float2(h[0]), p1 = __half22float2(h[1]);
    float2 p2 = __half22float2(h[2]), p3 = __half22float2(h[3]);
    acc[0] += p0.x; acc[1] += p0.y; acc[2] += p1.x; acc[3] += p1.y;
    acc[4] += p2.x; acc[5] += p2.y; acc[6] += p3.x; acc[7] += p3.y;
}

// ---- FUSED layer-1 gather SpMM + dense MLP. R13-exact (session best, 130.2us):
//      NPB=8, 256 thr, 4 waves x 2 nodes = 5000 waves. Sweep bracketed this optimum:
//      2500w=133.9 / 5000w=130.2 / 10000w@512thr=136.5 / 10000w@1024thr=147.2.
//      sched_barrier(0) = compile-time fence for the R6 compiler-hoist race (proven
//      safe R12/R13); waves stay decoupled (no sum-of-max barrier stalls).
__global__ void gather_mlp_kernel(const unsigned short* __restrict__ deg_in,
                                  const unsigned short* __restrict__ csr,
                                  const uint4* __restrict__ xh,
                                  const float* __restrict__ rs_out,
                                  const float* __restrict__ rs_in,
                                  const float* __restrict__ W1, const float* __restrict__ b1,
                                  const float* __restrict__ W2, __half* __restrict__ zh,
                                  int nN) {
    __shared__ float ts[NPB][NFEAT];           // 4 KB gather outputs
    __shared__ float h1[NPB][NFEAT];           // 4 KB hidden layer
    __shared__ unsigned short eids[4][PCAP];   // 1 KB
    int tid = threadIdx.x;
    int w = tid >> 6, lane = tid & 63;
    int i0 = blockIdx.x * NPB;                 // grid exact: nN/8
    int quad = lane >> 4;   // edge residue class
    int g = lane & 15;      // 16B chunk within 256B fp16 row

    for (int r = 0; r < 2; r++) {              // wave handles 2 nodes, decoupled
        int node = w * 2 + r;
        int i = i0 + node;
        int n = deg_in[i];
        ((unsigned int*)eids[w])[lane] =
            ((const unsigned int*)(csr + (size_t)i * PCAP))[lane];
        __builtin_amdgcn_sched_barrier(0);  // compiler fence (R12-proven)
        float s_in = rs_in[i];
        float acc[8] = {0.f, 0.f, 0.f, 0.f, 0.f, 0.f, 0.f, 0.f};
        int e = quad;
        for (; e + 28 < n; e += 32) {          // 8 edges of this quad in flight
            uint4 vv[8];
#pragma unroll
            for (int u = 0; u < 8; u++) {
                int s = eids[w][e + 4 * u];
                vv[u] = xh[(size_t)s * 16 + g];
            }
#pragma unroll
            for (int u = 0; u < 8; u++) add8(acc, vv[u]);
        }
        for (; e + 12 < n; e += 16) {
            uint4 vv[4];
#pragma unroll
            for (int u = 0; u < 4; u++) {
                int s = eids[w][e + 4 * u];
                vv[u] = xh[(size_t)s * 16 + g];
            }
#pragma unroll
            for (int u = 0; u < 4; u++) add8(acc, vv[u]);
        }
        for (; e < n; e += 4)
            add8(acc, xh[(size_t)eids[w][e] * 16 + g]);
#pragma unroll
        for (int d = 16; d <= 32; d <<= 1)
#pragma unroll
            for (int k = 0; k < 8; k++) acc[k] += __shfl_xor(acc[k], d);
        if (lane < 16) {
            float4 o0 = {acc[0] * s_in, acc[1] * s_in, acc[2] * s_in, acc[3] * s_in};
            float4 o1 = {acc[4] * s_in, acc[5] * s_in, acc[6] * s_in, acc[7] * s_in};
            float4* tp = (float4*)(&ts[node][g * 8]);
            tp[0] = o0; tp[1] = o1;
        }
        __builtin_amdgcn_sched_barrier(0);  // fence loop-carried WAR (no wave coupling)
    }
    __syncthreads();   // cross-wave: all 8 ts rows visible before MLP
    // ---- MLP tile, 256 threads, 8 nodes. Layer 1: 4 outputs/thread.
    {
        int j = tid & 127;
        int gq = (tid >> 7) * 4;               // nodes gq..gq+3
        float a[4];
        float bb = b1[j];
#pragma unroll
        for (int u = 0; u < 4; u++) a[u] = bb;
#pragma unroll 8
        for (int k = 0; k < NFEAT; k++) {
            float wv = W1[k * NFEAT + j];
#pragma unroll
            for (int u = 0; u < 4; u++) a[u] += ts[gq + u][k] * wv;
        }
#pragma unroll
        for (int u = 0; u < 4; u++) h1[gq + u][j] = fmaxf(a[u], 0.0f);
    }
    __syncthreads();
    // ---- Layer 2: 2 outputs/thread (8 nodes x 64 outs), write fp16 z
    {
        int j2 = tid & 63;
        int g2 = (tid >> 6) * 2;               // nodes g2, g2+1
        float c[2] = {0.f, 0.f};
#pragma unroll 8
        for (int k = 0; k < NFEAT; k++) {
            float wv = W2[k * NOUT + j2];
            c[0] += h1[g2][k] * wv;
            c[1] += h1[g2 + 1][k] * wv;
        }
#pragma unroll
        for (int u = 0; u < 2; u++)
            zh[(size_t)(i0 + g2 + u) * NOUT + j2] =
                __float2half_rn(c[u] * rs_out[i0 + g2 + u]);
    }
}

// ---- layer-2 gather SpMM: wave/node, 8 lanes/edge x 16B (R10-verbatim)
__global__ void gather2_kernel(const unsigned short* __restrict__ deg_in,
                               const unsigned short* __restrict__ csr,
                               const uint4* __restrict__ zh, const float* __restrict__ rs_in,
                               const float* __restrict__ b2, float* __restrict__ out, int nN) {
    __shared__ unsigned short eids[4][PCAP];
    int tid = threadIdx.x;
    int w = tid >> 6, lane = tid & 63;
    int i = blockIdx.x * 4 + w;
    int n = deg_in[i];
    ((unsigned int*)eids[w])[lane] = ((const unsigned int*)(csr + (size_t)i * PCAP))[lane];
    // no barrier: wave-private LDS, write-once/read-many (proven)

    int oct = lane >> 3;   // edge residue class (0..7)
    int g = lane & 7;      // 16B chunk within 128B fp16 row
    float acc[8] = {0.f, 0.f, 0.f, 0.f, 0.f, 0.f, 0.f, 0.f};
    int e = oct;
    for (; e + 56 < n; e += 64) {
        uint4 vv[8];
#pragma unroll
        for (int u = 0; u < 8; u++) vv[u] = zh[(size_t)eids[w][e + 8 * u] * 8 + g];
#pragma unroll
        for (int u = 0; u < 8; u++) add8(acc, vv[u]);
    }
    for (; e + 24 < n; e += 32) {
        uint4 vv[4];
#pragma unroll
        for (int u = 0; u < 4; u++) vv[u] = zh[(size_t)eids[w][e + 8 * u] * 8 + g];
#pragma unroll
        for (int u = 0; u < 4; u++) add8(acc, vv[u]);
    }
    for (; e < n; e += 8)
        add8(acc, zh[(size_t)eids[w][e] * 8 + g]);
#pragma unroll
    for (int d = 8; d <= 32; d <<= 1)
#pragma unroll
        for (int k = 0; k < 8; k++) acc[k] += __shfl_xor(acc[k], d);
    if (lane < 8) {
        float s = rs_in[i];
        float4 bb0 = ((const float4*)b2)[2 * g], bb1 = ((const float4*)b2)[2 * g + 1];
        float4 o0 = {acc[0] * s + bb0.x, acc[1] * s + bb0.y, acc[2] * s + bb0.z, acc[3] * s + bb0.w};
        float4 o1 = {acc[4] * s + bb1.x, acc[5] * s + bb1.y, acc[6] * s + bb1.z, acc[7] * s + bb1.w};
        float4* op = (float4*)(out + (size_t)i * NOUT + g * 8);
        op[0] = o0; op[1] = o1;
    }
}

extern "C" void kernel_launch(void* const* d_in, const int* in_sizes, int n_in,
                              void* d_out, int out_size, void* d_ws, size_t ws_size,
                              hipStream_t stream) {
    const float* x  = (const float*)d_in[0];
    const int* src  = (const int*)d_in[1];
    const int* dst  = (const int*)d_in[2];
    const float* W1 = (const float*)d_in[3];
    const float* b1 = (const float*)d_in[4];
    const float* W2 = (const float*)d_in[5];
    const float* b2 = (const float*)d_in[6];
    float* out = (float*)d_out;

    const int nN = in_sizes[0] / NFEAT;  // 10000
    const int nE = in_sizes[1];          // 640000

    // ---- workspace (~14.7 MB), byte-identical layout to R10/R12/R13
    char* p = (char*)d_ws;
    uint4* xh = (uint4*)p;                        p += (size_t)nN * NFEAT * 2;  // 2.56 MB fp16 (pre-scaled)
    unsigned char* hist_src = (unsigned char*)p;  p += (size_t)HB * nN;         // 2.56 MB
    unsigned char* hist_dst = (unsigned char*)p;  p += (size_t)HB * nN;         // 2.56 MB
    unsigned char* base_rel = (unsigned char*)p;  p += (size_t)HB * nN;         // 2.56 MB
    unsigned short* csr     = (unsigned short*)p; p += (size_t)nN * PCAP * 2;   // 2.56 MB
    unsigned short* deg_in  = (unsigned short*)p; p += (size_t)nN * 2;          // 20 KB
    float* rs_in  = (float*)p; p += (size_t)nN * sizeof(float);
    float* rs_out = (float*)p; p += (size_t)nN * sizeof(float);
    __half* zh = (__half*)p;   p += (size_t)nN * NOUT * 2;                      // 1.28 MB fp16

    // 1. histograms (TPB=1024)
    hist_kernel<<<HB, 1024, (size_t)nN * sizeof(int), stream>>>(
        src, dst, hist_src, hist_dst, nN, nE);
    // 2. bases + degrees + rsqrt (wave-per-4-nodes packed scan)
    {
        int waves = nN / 4;                       // 2500
        int blocks = (waves * 64 + 255) / 256;    // 625
        offsets_kernel<<<blocks, 256, 0, stream>>>(
            hist_src, hist_dst, base_rel, deg_in, rs_in, rs_out, nN);
    }
    // 3. scatter into CSR + fused x->fp16 pre-scaled (TPB=1024)
    scatter_kernel<<<HB, 1024, (size_t)nN * sizeof(int), stream>>>(
        src, dst, base_rel, x, rs_out, csr, xh, nN, nE);
    // 4. FUSED layer-1 gather SpMM + MLP (NPB=8, 2 nodes/wave: 5000 waves, 1250 blocks)
    gather_mlp_kernel<<<nN / NPB, 256, 0, stream>>>(
        deg_in, csr, xh, rs_out, rs_in, W1, b1, W2, zh, nN);
    // 5. layer-2 gather SpMM (R10-verbatim)
    gather2_kernel<<<nN / 4, 256, 0, stream>>>(
        deg_in, csr, (const uint4*)zh, rs_in, b2, out, nN);
}